// Round 7
// baseline (932.083 us; speedup 1.0000x reference)
//
#include <hip/hip_runtime.h>
#include <stdint.h>

#define NN 50000
#define NE 800000
#define NG 128
#define BN_EPS 1e-5f
#define NBUCKET 196        // ceil(NN/256)
#define BCAP 6144          // mean 4082, sigma 64 -> +32 sigma
#define OCAP 8192

typedef __attribute__((ext_vector_type(8))) __bf16 bf16x8;
typedef __attribute__((ext_vector_type(8))) unsigned short ushort8;
typedef __attribute__((ext_vector_type(4))) float floatx4;

__device__ inline unsigned short f2bf(float f) {
    union { float f; unsigned u; } x; x.f = f;
    unsigned u = x.u;
    return (unsigned short)((u + 0x7fffu + ((u >> 16) & 1u)) >> 16);
}
__device__ inline float bflo(unsigned u) {
    union { unsigned u; float f; } x; x.u = u << 16; return x.f;
}
__device__ inline float bfhi(unsigned u) {
    union { unsigned u; float f; } x; x.u = u & 0xffff0000u; return x.f;
}
__device__ inline unsigned pack_bf2(float a, float b) {
    union { struct { __bf16 x, y; } s; unsigned u; } t;
    t.s.x = (__bf16)a; t.s.y = (__bf16)b; return t.u;
}
__device__ inline bf16x8 as_bf(ushort8 u) {
    union { ushort8 u; bf16x8 b; } x; x.u = u; return x.b;
}

// ---------------- CSR build ----------------

__global__ void hist_kernel(const int* __restrict__ dst, int* __restrict__ deg, int E) {
    int e = blockIdx.x * 256 + threadIdx.x;
    if (e < E) atomicAdd(&deg[dst[e]], 1);
}

__global__ void scan1_kernel(const int* __restrict__ deg, int* __restrict__ row_ptr,
                             int* __restrict__ blocksum, int n) {
    __shared__ int s[256];
    int i = blockIdx.x * 256 + threadIdx.x;
    int v = (i < n) ? deg[i] : 0;
    s[threadIdx.x] = v;
    __syncthreads();
    for (int off = 1; off < 256; off <<= 1) {
        int t = (threadIdx.x >= off) ? s[threadIdx.x - off] : 0;
        __syncthreads();
        s[threadIdx.x] += t;
        __syncthreads();
    }
    if (i < n) row_ptr[i + 1] = s[threadIdx.x];
    if (threadIdx.x == 255) blocksum[blockIdx.x] = s[255];
}

__global__ void scan2_kernel(int* __restrict__ blocksum, int nb) {
    __shared__ int s[256];
    int v = (threadIdx.x < nb) ? blocksum[threadIdx.x] : 0;
    s[threadIdx.x] = v;
    __syncthreads();
    for (int off = 1; off < 256; off <<= 1) {
        int t = (threadIdx.x >= off) ? s[threadIdx.x - off] : 0;
        __syncthreads();
        s[threadIdx.x] += t;
        __syncthreads();
    }
    if (threadIdx.x < nb) blocksum[threadIdx.x] = s[threadIdx.x] - v;
}

__global__ void scan3_kernel(int* __restrict__ row_ptr, const int* __restrict__ blocksum, int n) {
    int i = blockIdx.x * 256 + threadIdx.x;
    if (i < n) row_ptr[i + 1] += blocksum[blockIdx.x];
    if (i == 0) row_ptr[0] = 0;
}

// pass A: bin edges by dst>>8; packed (dst<<16)|src (ids < 2^16)
__global__ void binA_kernel(const int* __restrict__ src, const int* __restrict__ dst,
                            unsigned* __restrict__ bbuf, int* __restrict__ bcnt,
                            unsigned* __restrict__ obuf, int* __restrict__ ocnt, int E) {
    int e = blockIdx.x * 256 + threadIdx.x;
    if (e >= E) return;
    int d = dst[e], s = src[e];
    int b = d >> 8;
    unsigned pk = ((unsigned)d << 16) | (unsigned)s;
    int p = atomicAdd(&bcnt[b], 1);
    if (p < BCAP) bbuf[(size_t)b * BCAP + p] = pk;
    else { int o = atomicAdd(ocnt, 1); if (o < OCAP) obuf[o] = pk; }
}

// pass B: block per bucket -> L2-local scatter into col
__global__ void binB_kernel(const unsigned* __restrict__ bbuf, const int* __restrict__ bcnt,
                            const int* __restrict__ row_ptr, int* __restrict__ pos,
                            int* __restrict__ col,
                            const unsigned* __restrict__ obuf, const int* __restrict__ ocnt) {
    int b = blockIdx.x;
    if (b < NBUCKET) {
        int cnt = min(bcnt[b], BCAP);
        const unsigned* p = bbuf + (size_t)b * BCAP;
        for (int i = threadIdx.x; i < cnt; i += 256) {
            unsigned e = p[i];
            int d = e >> 16, s = e & 0xffff;
            int q = atomicAdd(&pos[d], 1);
            col[row_ptr[d] + q] = s;
        }
    } else {
        int cnt = min(*ocnt, OCAP);
        for (int i = threadIdx.x; i < cnt; i += 256) {
            unsigned e = obuf[i];
            int d = e >> 16, s = e & 0xffff;
            int q = atomicAdd(&pos[d], 1);
            col[row_ptr[d] + q] = s;
        }
    }
}

// ---------------- weight prep ----------------

struct PrepArgs {
    const float* w1[5]; const float* w2[5];
    const float* b1[5]; const float* ig[5]; const float* ib[5];
    const float* im[5]; const float* iv[5]; const float* b2[5];
    const float* og; const float* ob; const float* om; const float* ov;
    unsigned short* w1t[5]; unsigned short* w2t[5];
    float* s1[5]; float* c1[5]; float* s2[5]; float* c2[5];
};

__global__ void prep_kernel(PrepArgs p) {
    int layer = blockIdx.x;
    int K = (layer == 0) ? 128 : 64;
    int kshift = (layer == 0) ? 7 : 6;
    const float* w1 = p.w1[layer];
    unsigned short* w1t = p.w1t[layer];
    for (int idx = threadIdx.x; idx < 128 * K; idx += blockDim.x) {
        int c = idx >> kshift, k = idx & (K - 1);
        w1t[idx] = f2bf(w1[k * 128 + c]);
    }
    const float* w2 = p.w2[layer];
    unsigned short* w2t = p.w2t[layer];
    for (int idx = threadIdx.x; idx < 64 * 128; idx += blockDim.x) {
        int c = idx >> 7, k = idx & 127;
        w2t[idx] = f2bf(w2[k * 64 + c]);
    }
    if (threadIdx.x < 128) {
        int ch = threadIdx.x;
        float s = p.ig[layer][ch] * rsqrtf(p.iv[layer][ch] + BN_EPS);
        p.s1[layer][ch] = s;
        p.c1[layer][ch] = (p.b1[layer][ch] - p.im[layer][ch]) * s + p.ib[layer][ch];
        if (ch < 64) {
            float s2v = p.og[layer * 64 + ch] * rsqrtf(p.ov[layer * 64 + ch] + BN_EPS);
            p.s2[layer][ch] = s2v;
            p.c2[layer][ch] = (p.b2[layer][ch] - p.om[layer * 64 + ch]) * s2v + p.ob[layer * 64 + ch];
        }
    }
}

// ---------------- x fp32 -> bf16 ----------------

__global__ void xcvt_kernel(const float* __restrict__ x, unsigned* __restrict__ xb, int npair) {
    int i = blockIdx.x * 256 + threadIdx.x;
    if (i < npair) {
        float2 v = ((const float2*)x)[i];
        xb[i] = pack_bf2(v.x, v.y);
    }
}

// ---------------- aggregation: channel-split for L2 residency ----------------
// DW = dwords per row (64 for D=128, 32 for D=64); each pass handles 16 dwords
// (64B slice) so the gather table per pass is 3.2 MB -> fits per-XCD L2.
// 16-lane group per node; gridDim.y = DW/16 passes.

template <int DW>
__global__ void agg_split(const unsigned* __restrict__ hr, const int* __restrict__ rp,
                          const int* __restrict__ col, unsigned* __restrict__ y, int n) {
    int node = blockIdx.x * 16 + (threadIdx.x >> 4);
    int l = threadIdx.x & 15;
    if (node >= n) return;
    const unsigned* base = hr + blockIdx.y * 16 + l;
    unsigned u = base[(size_t)node * DW];
    float a0 = bflo(u), a1 = bfhi(u);
    int beg = rp[node], end = rp[node + 1];
    int e = beg;
    for (; e + 4 <= end; e += 4) {
        unsigned v0 = base[(size_t)col[e]     * DW];
        unsigned v1 = base[(size_t)col[e + 1] * DW];
        unsigned v2 = base[(size_t)col[e + 2] * DW];
        unsigned v3 = base[(size_t)col[e + 3] * DW];
        a0 += bflo(v0); a1 += bfhi(v0);
        a0 += bflo(v1); a1 += bfhi(v1);
        a0 += bflo(v2); a1 += bfhi(v2);
        a0 += bflo(v3); a1 += bfhi(v3);
    }
    for (; e < end; ++e) {
        unsigned v = base[(size_t)col[e] * DW];
        a0 += bflo(v); a1 += bfhi(v);
    }
    y[(size_t)node * DW + blockIdx.y * 16 + l] = pack_bf2(a0, a1);
}

// ---------------- fused MLP via MFMA ----------------

template <int K>
__launch_bounds__(256, 3)
__global__ void mlp_mfma(const unsigned short* __restrict__ yb, unsigned short* __restrict__ hb,
                         const unsigned short* __restrict__ w1t,  // [128][K] bf16
                         const unsigned short* __restrict__ w2t,  // [64][128] bf16
                         const float* __restrict__ s1, const float* __restrict__ c1,
                         const float* __restrict__ s2, const float* __restrict__ c2,
                         int n) {
    __shared__ float zl[64 * 132];
    const int tid = threadIdx.x;
    const int w = tid >> 6;
    const int l = tid & 63;
    const int l15 = l & 15, lg = l >> 4;
    const int node0 = blockIdx.x * 64;

    // ---- GEMM1: Z[64x128] = Y[64xK] @ W1[Kx128]
    const int arow = node0 + w * 16 + l15;
    const int arow_c = min(arow, n - 1);
    bf16x8 afr[K / 32];
#pragma unroll
    for (int ks = 0; ks < K / 32; ++ks)
        afr[ks] = as_bf(*(const ushort8*)(yb + (size_t)arow_c * K + ks * 32 + lg * 8));

#pragma unroll
    for (int cc = 0; cc < 8; ++cc) {
        floatx4 acc = {0.f, 0.f, 0.f, 0.f};
#pragma unroll
        for (int ks = 0; ks < K / 32; ++ks) {
            bf16x8 bfr = as_bf(*(const ushort8*)(w1t + (size_t)(cc * 16 + l15) * K + ks * 32 + lg * 8));
            acc = __builtin_amdgcn_mfma_f32_16x16x32_bf16(afr[ks], bfr, acc, 0, 0, 0);
        }
        int ch = cc * 16 + l15;
        float s = s1[ch], c = c1[ch];
#pragma unroll
        for (int r = 0; r < 4; ++r) {
            int row = w * 16 + lg * 4 + r;
            zl[row * 132 + ch] = fmaxf(acc[r] * s + c, 0.f);
        }
    }
    __syncthreads();

    // ---- GEMM2: H[64x64] = Zr[64x128] @ W2[128x64]
    floatx4 acc2[4];
#pragma unroll
    for (int ct = 0; ct < 4; ++ct) acc2[ct] = (floatx4){0.f, 0.f, 0.f, 0.f};

#pragma unroll
    for (int ks = 0; ks < 4; ++ks) {
        const float* zp = &zl[(w * 16 + l15) * 132 + ks * 32 + lg * 8];
        float4 za = *(const float4*)zp;
        float4 zb = *(const float4*)(zp + 4);
        bf16x8 a2;
        a2[0] = (__bf16)za.x; a2[1] = (__bf16)za.y; a2[2] = (__bf16)za.z; a2[3] = (__bf16)za.w;
        a2[4] = (__bf16)zb.x; a2[5] = (__bf16)zb.y; a2[6] = (__bf16)zb.z; a2[7] = (__bf16)zb.w;
#pragma unroll
        for (int ct = 0; ct < 4; ++ct) {
            bf16x8 b2 = as_bf(*(const ushort8*)(w2t + (size_t)(ct * 16 + l15) * 128 + ks * 32 + lg * 8));
            acc2[ct] = __builtin_amdgcn_mfma_f32_16x16x32_bf16(a2, b2, acc2[ct], 0, 0, 0);
        }
    }
    __syncthreads();

    // ---- BN2 + ReLU -> per-wave H region, then coalesced bf16 store
    float* Hp = zl + w * 2112;
#pragma unroll
    for (int ct = 0; ct < 4; ++ct) {
        int ch = ct * 16 + l15;
        float s = s2[ch], c = c2[ch];
#pragma unroll
        for (int r = 0; r < 4; ++r)
            Hp[(lg * 4 + r) * 68 + ch] = fmaxf(acc2[ct][r] * s + c, 0.f);
    }
    __syncthreads();

    int nr = l >> 2, ch0 = (l & 3) * 16;
    int node = node0 + w * 16 + nr;
    if (node < n) {
        const float* q = Hp + nr * 68 + ch0;
        ushort8 u0, u1;
#pragma unroll
        for (int j = 0; j < 8; ++j) { union { __bf16 b; unsigned short s; } t; t.b = (__bf16)q[j]; u0[j] = t.s; }
#pragma unroll
        for (int j = 0; j < 8; ++j) { union { __bf16 b; unsigned short s; } t; t.b = (__bf16)q[8 + j]; u1[j] = t.s; }
        *(ushort8*)(hb + (size_t)node * 64 + ch0) = u0;
        *(ushort8*)(hb + (size_t)node * 64 + ch0 + 8) = u1;
    }
}

// ---------------- pooling (batch sorted): half-wave per 32 nodes ----------------

__global__ void pool_kernel(const unsigned short* __restrict__ h, const int* __restrict__ batch,
                            float* __restrict__ sums, int* __restrict__ cnt, int n) {
    int hw = (blockIdx.x * 256 + threadIdx.x) >> 5;
    int l = threadIdx.x & 31;
    int n0 = hw * 32;
    if (n0 >= n) return;
    int n1 = min(n0 + 32, n);
    const unsigned* hr = (const unsigned*)h;
    float a0 = 0.f, a1 = 0.f; int c = 0;
    int g_cur = batch[n0];
    for (int i = n0; i < n1; ++i) {
        int g = batch[i];
        if (g != g_cur) {
            atomicAdd(&sums[g_cur * 64 + 2 * l], a0);
            atomicAdd(&sums[g_cur * 64 + 2 * l + 1], a1);
            if (l == 0) atomicAdd(&cnt[g_cur], c);
            a0 = a1 = 0.f; c = 0; g_cur = g;
        }
        unsigned u = hr[(size_t)i * 32 + l];
        a0 += bflo(u); a1 += bfhi(u);
        c++;
    }
    atomicAdd(&sums[g_cur * 64 + 2 * l], a0);
    atomicAdd(&sums[g_cur * 64 + 2 * l + 1], a1);
    if (l == 0) atomicAdd(&cnt[g_cur], c);
}

__global__ void finalize_kernel(const float* __restrict__ sums, const int* __restrict__ cnt,
                                float* __restrict__ out) {
    int i = blockIdx.x * 256 + threadIdx.x;
    if (i < NG * 64) {
        float c = (float)cnt[i >> 6];
        out[i] = sums[i] / fmaxf(c, 1.f);
    }
}

// ---------------- launcher ----------------

extern "C" void kernel_launch(void* const* d_in, const int* in_sizes, int n_in,
                              void* d_out, int out_size, void* d_ws, size_t ws_size,
                              hipStream_t stream) {
    const float* x    = (const float*)d_in[0];
    const int*  ei    = (const int*)d_in[1];
    const int*  batch = (const int*)d_in[2];
    const float* w1_0 = (const float*)d_in[3];
    const float* b1_0 = (const float*)d_in[4];
    const float* ig0  = (const float*)d_in[5];
    const float* ib0  = (const float*)d_in[6];
    const float* im0  = (const float*)d_in[7];
    const float* iv0  = (const float*)d_in[8];
    const float* w2_0 = (const float*)d_in[9];
    const float* b2_0 = (const float*)d_in[10];
    const float* W1s  = (const float*)d_in[11];
    const float* b1s  = (const float*)d_in[12];
    const float* IG   = (const float*)d_in[13];
    const float* IB   = (const float*)d_in[14];
    const float* IM   = (const float*)d_in[15];
    const float* IV   = (const float*)d_in[16];
    const float* W2s  = (const float*)d_in[17];
    const float* b2s  = (const float*)d_in[18];
    const float* OG   = (const float*)d_in[19];
    const float* OB   = (const float*)d_in[20];
    const float* OM   = (const float*)d_in[21];
    const float* OV   = (const float*)d_in[22];
    float* out = (float*)d_out;

    const int N = NN, E = NE;
    const int* src = ei;
    const int* dst = ei + E;

    char* ws = (char*)d_ws;
    size_t off = 0;
    auto alloc = [&](size_t bytes) -> void* {
        void* p = ws + off;
        off += (bytes + 255) & ~(size_t)255;
        return p;
    };
    int*   row_ptr  = (int*)alloc((N + 1) * sizeof(int));
    int*   blocksum = (int*)alloc(256 * sizeof(int));
    // ---- contiguous zero region ----
    char*  zbase    = ws + off;
    int*   deg      = (int*)alloc(N * sizeof(int));
    int*   pos      = (int*)alloc(N * sizeof(int));
    int*   bcnt     = (int*)alloc(NBUCKET * sizeof(int));
    int*   ocnt     = (int*)alloc(sizeof(int));
    float* sums     = (float*)alloc(NG * 64 * sizeof(float));
    int*   cnt      = (int*)alloc(NG * sizeof(int));
    size_t zlen     = (ws + off) - zbase;
    // ---- rest ----
    int*   col      = (int*)alloc((size_t)E * sizeof(int));
    unsigned* bbuf  = (unsigned*)alloc((size_t)NBUCKET * BCAP * 4);
    unsigned* obuf  = (unsigned*)alloc(OCAP * 4);
    unsigned* xb    = (unsigned*)alloc((size_t)N * 64 * 4);
    unsigned short* ybuf = (unsigned short*)alloc((size_t)N * 128 * 2);
    unsigned short* hbuf = (unsigned short*)alloc((size_t)N * 64 * 2);
    unsigned short* w1t  = (unsigned short*)alloc(49152 * 2);
    unsigned short* w2t  = (unsigned short*)alloc(5 * 64 * 128 * 2);
    float* s1 = (float*)alloc(5 * 128 * sizeof(float));
    float* c1 = (float*)alloc(5 * 128 * sizeof(float));
    float* s2 = (float*)alloc(5 * 64 * sizeof(float));
    float* c2 = (float*)alloc(5 * 64 * sizeof(float));

    const int NB = (N + 255) / 256;
    const int EB = (E + 255) / 256;

    hipMemsetAsync(zbase, 0, zlen, stream);

    PrepArgs p;
    p.w1[0] = w1_0; p.w2[0] = w2_0; p.b1[0] = b1_0; p.ig[0] = ig0; p.ib[0] = ib0;
    p.im[0] = im0; p.iv[0] = iv0; p.b2[0] = b2_0;
    for (int i = 1; i < 5; ++i) {
        p.w1[i] = W1s + (size_t)(i - 1) * 64 * 128;
        p.w2[i] = W2s + (size_t)(i - 1) * 128 * 64;
        p.b1[i] = b1s + (i - 1) * 128;
        p.ig[i] = IG + (i - 1) * 128; p.ib[i] = IB + (i - 1) * 128;
        p.im[i] = IM + (i - 1) * 128; p.iv[i] = IV + (i - 1) * 128;
        p.b2[i] = b2s + (i - 1) * 64;
    }
    p.og = OG; p.ob = OB; p.om = OM; p.ov = OV;
    p.w1t[0] = w1t;
    for (int i = 1; i < 5; ++i) p.w1t[i] = w1t + 16384 + (size_t)(i - 1) * 8192;
    for (int i = 0; i < 5; ++i) {
        p.w2t[i] = w2t + (size_t)i * 8192;
        p.s1[i] = s1 + i * 128; p.c1[i] = c1 + i * 128;
        p.s2[i] = s2 + i * 64;  p.c2[i] = c2 + i * 64;
    }
    prep_kernel<<<5, 256, 0, stream>>>(p);

    // CSR: hist -> scan -> binned fill
    hist_kernel<<<EB, 256, 0, stream>>>(dst, deg, E);
    scan1_kernel<<<NB, 256, 0, stream>>>(deg, row_ptr, blocksum, N);
    scan2_kernel<<<1, 256, 0, stream>>>(blocksum, NB);
    scan3_kernel<<<NB, 256, 0, stream>>>(row_ptr, blocksum, N);
    binA_kernel<<<EB, 256, 0, stream>>>(src, dst, bbuf, bcnt, obuf, ocnt, E);
    binB_kernel<<<NBUCKET + 1, 256, 0, stream>>>(bbuf, bcnt, row_ptr, pos, col, obuf, ocnt);

    xcvt_kernel<<<(N * 64 + 255) / 256, 256, 0, stream>>>(x, xb, N * 64);

    const int MGB = (N + 63) / 64;
    const int ANB = (N + 15) / 16;   // 3125

    // layer 0
    agg_split<64><<<dim3(ANB, 4), 256, 0, stream>>>(xb, row_ptr, col, (unsigned*)ybuf, N);
    mlp_mfma<128><<<MGB, 256, 0, stream>>>(ybuf, hbuf, p.w1t[0], p.w2t[0],
                                           p.s1[0], p.c1[0], p.s2[0], p.c2[0], N);
    // layers 1..4
    for (int i = 1; i < 5; ++i) {
        agg_split<32><<<dim3(ANB, 2), 256, 0, stream>>>((const unsigned*)hbuf, row_ptr, col,
                                                        (unsigned*)ybuf, N);
        mlp_mfma<64><<<MGB, 256, 0, stream>>>(ybuf, hbuf, p.w1t[i], p.w2t[i],
                                              p.s1[i], p.c1[i], p.s2[i], p.c2[i], N);
    }

    pool_kernel<<<NB, 256, 0, stream>>>(hbuf, batch, sums, cnt, N);
    finalize_kernel<<<32, 256, 0, stream>>>(sums, cnt, out);
}

// Round 12
// 477.099 us; speedup vs baseline: 1.9536x; 1.9536x over previous
//
#include <hip/hip_runtime.h>
#include <stdint.h>

#define NN 50000
#define NE 800000
#define NG 128
#define BN_EPS 1e-5f

typedef __attribute__((ext_vector_type(8))) __bf16 bf16x8;
typedef __attribute__((ext_vector_type(8))) unsigned short ushort8;
typedef __attribute__((ext_vector_type(4))) float floatx4;

__device__ inline unsigned short f2bf(float f) {
    union { float f; unsigned u; } x; x.f = f;
    unsigned u = x.u;
    return (unsigned short)((u + 0x7fffu + ((u >> 16) & 1u)) >> 16);
}
__device__ inline float bflo(unsigned u) {
    union { unsigned u; float f; } x; x.u = u << 16; return x.f;
}
__device__ inline float bfhi(unsigned u) {
    union { unsigned u; float f; } x; x.u = u & 0xffff0000u; return x.f;
}
__device__ inline unsigned pack_bf2(float a, float b) {
    union { struct { __bf16 x, y; } s; unsigned u; } t;
    t.s.x = (__bf16)a; t.s.y = (__bf16)b; return t.u;
}
__device__ inline bf16x8 as_bf(ushort8 u) {
    union { ushort8 u; bf16x8 b; } x; x.u = u; return x.b;
}

// ---------------- CSR build ----------------

// single atomic pass: histogram + per-edge rank
__global__ void rank_kernel(const int* __restrict__ dst, int* __restrict__ deg,
                            int* __restrict__ rank, int E) {
    int e = blockIdx.x * 256 + threadIdx.x;
    if (e < E) rank[e] = atomicAdd(&deg[dst[e]], 1);
}

__global__ void scan1_kernel(const int* __restrict__ deg, int* __restrict__ row_ptr,
                             int* __restrict__ blocksum, int n) {
    __shared__ int s[256];
    int i = blockIdx.x * 256 + threadIdx.x;
    int v = (i < n) ? deg[i] : 0;
    s[threadIdx.x] = v;
    __syncthreads();
    for (int off = 1; off < 256; off <<= 1) {
        int t = (threadIdx.x >= off) ? s[threadIdx.x - off] : 0;
        __syncthreads();
        s[threadIdx.x] += t;
        __syncthreads();
    }
    if (i < n) row_ptr[i + 1] = s[threadIdx.x];
    if (threadIdx.x == 255) blocksum[blockIdx.x] = s[255];
}

__global__ void scan2_kernel(int* __restrict__ blocksum, int nb) {
    __shared__ int s[256];
    int v = (threadIdx.x < nb) ? blocksum[threadIdx.x] : 0;
    s[threadIdx.x] = v;
    __syncthreads();
    for (int off = 1; off < 256; off <<= 1) {
        int t = (threadIdx.x >= off) ? s[threadIdx.x - off] : 0;
        __syncthreads();
        s[threadIdx.x] += t;
        __syncthreads();
    }
    if (threadIdx.x < nb) blocksum[threadIdx.x] = s[threadIdx.x] - v;
}

__global__ void scan3_kernel(int* __restrict__ row_ptr, const int* __restrict__ blocksum, int n) {
    int i = blockIdx.x * 256 + threadIdx.x;
    if (i < n) row_ptr[i + 1] += blocksum[blockIdx.x];
    if (i == 0) row_ptr[0] = 0;
}

// atomic-free scatter (rank precomputed); col is ushort (src < 2^16)
__global__ void fill2_kernel(const int* __restrict__ src, const int* __restrict__ dst,
                             const int* __restrict__ rank, const int* __restrict__ row_ptr,
                             unsigned short* __restrict__ col, int E) {
    int e = blockIdx.x * 256 + threadIdx.x;
    if (e < E) {
        int d = dst[e];
        col[row_ptr[d] + rank[e]] = (unsigned short)src[e];
    }
}

// ---------------- weight prep ----------------

struct PrepArgs {
    const float* w1[5]; const float* w2[5];
    const float* b1[5]; const float* ig[5]; const float* ib[5];
    const float* im[5]; const float* iv[5]; const float* b2[5];
    const float* og; const float* ob; const float* om; const float* ov;
    unsigned short* w1t[5]; unsigned short* w2t[5];
    float* s1[5]; float* c1[5]; float* s2[5]; float* c2[5];
};

__global__ void prep_kernel(PrepArgs p) {
    int layer = blockIdx.x;
    int K = (layer == 0) ? 128 : 64;
    int kshift = (layer == 0) ? 7 : 6;
    const float* w1 = p.w1[layer];
    unsigned short* w1t = p.w1t[layer];
    for (int idx = threadIdx.x; idx < 128 * K; idx += blockDim.x) {
        int c = idx >> kshift, k = idx & (K - 1);
        w1t[idx] = f2bf(w1[k * 128 + c]);
    }
    const float* w2 = p.w2[layer];
    unsigned short* w2t = p.w2t[layer];
    for (int idx = threadIdx.x; idx < 64 * 128; idx += blockDim.x) {
        int c = idx >> 7, k = idx & 127;
        w2t[idx] = f2bf(w2[k * 64 + c]);
    }
    if (threadIdx.x < 128) {
        int ch = threadIdx.x;
        float s = p.ig[layer][ch] * rsqrtf(p.iv[layer][ch] + BN_EPS);
        p.s1[layer][ch] = s;
        p.c1[layer][ch] = (p.b1[layer][ch] - p.im[layer][ch]) * s + p.ib[layer][ch];
        if (ch < 64) {
            float s2v = p.og[layer * 64 + ch] * rsqrtf(p.ov[layer * 64 + ch] + BN_EPS);
            p.s2[layer][ch] = s2v;
            p.c2[layer][ch] = (p.b2[layer][ch] - p.om[layer * 64 + ch]) * s2v + p.ob[layer * 64 + ch];
        }
    }
}

// ---------------- x fp32 -> bf16 ----------------

__global__ void xcvt_kernel(const float* __restrict__ x, unsigned* __restrict__ xb, int npair) {
    int i = blockIdx.x * 256 + threadIdx.x;
    if (i < npair) {
        float2 v = ((const float2*)x)[i];
        xb[i] = pack_bf2(v.x, v.y);
    }
}

// ---------------- aggregation: channel-split for L2 residency ----------------
// DW = dwords per row; each pass handles a 64B slice so the gather table per
// pass is 3.2 MB -> fits per-XCD L2. 16-lane group per node.

template <int DW>
__global__ void agg_split(const unsigned* __restrict__ hr, const int* __restrict__ rp,
                          const unsigned short* __restrict__ col, unsigned* __restrict__ y, int n) {
    int node = blockIdx.x * 16 + (threadIdx.x >> 4);
    int l = threadIdx.x & 15;
    if (node >= n) return;
    const unsigned* base = hr + blockIdx.y * 16 + l;
    unsigned u = base[(size_t)node * DW];
    float a0 = bflo(u), a1 = bfhi(u);
    int beg = rp[node], end = rp[node + 1];
    int e = beg;
    for (; e + 4 <= end; e += 4) {
        unsigned v0 = base[(size_t)col[e]     * DW];
        unsigned v1 = base[(size_t)col[e + 1] * DW];
        unsigned v2 = base[(size_t)col[e + 2] * DW];
        unsigned v3 = base[(size_t)col[e + 3] * DW];
        a0 += bflo(v0); a1 += bfhi(v0);
        a0 += bflo(v1); a1 += bfhi(v1);
        a0 += bflo(v2); a1 += bfhi(v2);
        a0 += bflo(v3); a1 += bfhi(v3);
    }
    for (; e < end; ++e) {
        unsigned v = base[(size_t)col[e] * DW];
        a0 += bflo(v); a1 += bfhi(v);
    }
    y[(size_t)node * DW + blockIdx.y * 16 + l] = pack_bf2(a0, a1);
}

// ---------------- fused MLP via MFMA ----------------

template <int K>
__launch_bounds__(256, 3)
__global__ void mlp_mfma(const unsigned short* __restrict__ yb, unsigned short* __restrict__ hb,
                         const unsigned short* __restrict__ w1t,  // [128][K] bf16
                         const unsigned short* __restrict__ w2t,  // [64][128] bf16
                         const float* __restrict__ s1, const float* __restrict__ c1,
                         const float* __restrict__ s2, const float* __restrict__ c2,
                         int n) {
    __shared__ float zl[64 * 132];
    const int tid = threadIdx.x;
    const int w = tid >> 6;
    const int l = tid & 63;
    const int l15 = l & 15, lg = l >> 4;
    const int node0 = blockIdx.x * 64;

    // ---- GEMM1: Z[64x128] = Y[64xK] @ W1[Kx128]
    const int arow = node0 + w * 16 + l15;
    const int arow_c = min(arow, n - 1);
    bf16x8 afr[K / 32];
#pragma unroll
    for (int ks = 0; ks < K / 32; ++ks)
        afr[ks] = as_bf(*(const ushort8*)(yb + (size_t)arow_c * K + ks * 32 + lg * 8));

#pragma unroll
    for (int cc = 0; cc < 8; ++cc) {
        floatx4 acc = {0.f, 0.f, 0.f, 0.f};
#pragma unroll
        for (int ks = 0; ks < K / 32; ++ks) {
            bf16x8 bfr = as_bf(*(const ushort8*)(w1t + (size_t)(cc * 16 + l15) * K + ks * 32 + lg * 8));
            acc = __builtin_amdgcn_mfma_f32_16x16x32_bf16(afr[ks], bfr, acc, 0, 0, 0);
        }
        int ch = cc * 16 + l15;
        float s = s1[ch], c = c1[ch];
#pragma unroll
        for (int r = 0; r < 4; ++r) {
            int row = w * 16 + lg * 4 + r;
            zl[row * 132 + ch] = fmaxf(acc[r] * s + c, 0.f);
        }
    }
    __syncthreads();

    // ---- GEMM2: H[64x64] = Zr[64x128] @ W2[128x64]
    floatx4 acc2[4];
#pragma unroll
    for (int ct = 0; ct < 4; ++ct) acc2[ct] = (floatx4){0.f, 0.f, 0.f, 0.f};

#pragma unroll
    for (int ks = 0; ks < 4; ++ks) {
        const float* zp = &zl[(w * 16 + l15) * 132 + ks * 32 + lg * 8];
        float4 za = *(const float4*)zp;
        float4 zb = *(const float4*)(zp + 4);
        bf16x8 a2;
        a2[0] = (__bf16)za.x; a2[1] = (__bf16)za.y; a2[2] = (__bf16)za.z; a2[3] = (__bf16)za.w;
        a2[4] = (__bf16)zb.x; a2[5] = (__bf16)zb.y; a2[6] = (__bf16)zb.z; a2[7] = (__bf16)zb.w;
#pragma unroll
        for (int ct = 0; ct < 4; ++ct) {
            bf16x8 b2 = as_bf(*(const ushort8*)(w2t + (size_t)(ct * 16 + l15) * 128 + ks * 32 + lg * 8));
            acc2[ct] = __builtin_amdgcn_mfma_f32_16x16x32_bf16(a2, b2, acc2[ct], 0, 0, 0);
        }
    }
    __syncthreads();

    // ---- BN2 + ReLU -> per-wave H region, then coalesced bf16 store
    float* Hp = zl + w * 2112;
#pragma unroll
    for (int ct = 0; ct < 4; ++ct) {
        int ch = ct * 16 + l15;
        float s = s2[ch], c = c2[ch];
#pragma unroll
        for (int r = 0; r < 4; ++r)
            Hp[(lg * 4 + r) * 68 + ch] = fmaxf(acc2[ct][r] * s + c, 0.f);
    }
    __syncthreads();

    int nr = l >> 2, ch0 = (l & 3) * 16;
    int node = node0 + w * 16 + nr;
    if (node < n) {
        const float* q = Hp + nr * 68 + ch0;
        ushort8 u0, u1;
#pragma unroll
        for (int j = 0; j < 8; ++j) { union { __bf16 b; unsigned short s; } t; t.b = (__bf16)q[j]; u0[j] = t.s; }
#pragma unroll
        for (int j = 0; j < 8; ++j) { union { __bf16 b; unsigned short s; } t; t.b = (__bf16)q[8 + j]; u1[j] = t.s; }
        *(ushort8*)(hb + (size_t)node * 64 + ch0) = u0;
        *(ushort8*)(hb + (size_t)node * 64 + ch0 + 8) = u1;
    }
}

// ---------------- pooling (batch sorted): half-wave per 32 nodes ----------------

__global__ void pool_kernel(const unsigned short* __restrict__ h, const int* __restrict__ batch,
                            float* __restrict__ sums, int* __restrict__ cnt, int n) {
    int hw = (blockIdx.x * 256 + threadIdx.x) >> 5;
    int l = threadIdx.x & 31;
    int n0 = hw * 32;
    if (n0 >= n) return;
    int n1 = min(n0 + 32, n);
    const unsigned* hr = (const unsigned*)h;
    float a0 = 0.f, a1 = 0.f; int c = 0;
    int g_cur = batch[n0];
    for (int i = n0; i < n1; ++i) {
        int g = batch[i];
        if (g != g_cur) {
            atomicAdd(&sums[g_cur * 64 + 2 * l], a0);
            atomicAdd(&sums[g_cur * 64 + 2 * l + 1], a1);
            if (l == 0) atomicAdd(&cnt[g_cur], c);
            a0 = a1 = 0.f; c = 0; g_cur = g;
        }
        unsigned u = hr[(size_t)i * 32 + l];
        a0 += bflo(u); a1 += bfhi(u);
        c++;
    }
    atomicAdd(&sums[g_cur * 64 + 2 * l], a0);
    atomicAdd(&sums[g_cur * 64 + 2 * l + 1], a1);
    if (l == 0) atomicAdd(&cnt[g_cur], c);
}

__global__ void finalize_kernel(const float* __restrict__ sums, const int* __restrict__ cnt,
                                float* __restrict__ out) {
    int i = blockIdx.x * 256 + threadIdx.x;
    if (i < NG * 64) {
        float c = (float)cnt[i >> 6];
        out[i] = sums[i] / fmaxf(c, 1.f);
    }
}

// ---------------- launcher ----------------

extern "C" void kernel_launch(void* const* d_in, const int* in_sizes, int n_in,
                              void* d_out, int out_size, void* d_ws, size_t ws_size,
                              hipStream_t stream) {
    const float* x    = (const float*)d_in[0];
    const int*  ei    = (const int*)d_in[1];
    const int*  batch = (const int*)d_in[2];
    const float* w1_0 = (const float*)d_in[3];
    const float* b1_0 = (const float*)d_in[4];
    const float* ig0  = (const float*)d_in[5];
    const float* ib0  = (const float*)d_in[6];
    const float* im0  = (const float*)d_in[7];
    const float* iv0  = (const float*)d_in[8];
    const float* w2_0 = (const float*)d_in[9];
    const float* b2_0 = (const float*)d_in[10];
    const float* W1s  = (const float*)d_in[11];
    const float* b1s  = (const float*)d_in[12];
    const float* IG   = (const float*)d_in[13];
    const float* IB   = (const float*)d_in[14];
    const float* IM   = (const float*)d_in[15];
    const float* IV   = (const float*)d_in[16];
    const float* W2s  = (const float*)d_in[17];
    const float* b2s  = (const float*)d_in[18];
    const float* OG   = (const float*)d_in[19];
    const float* OB   = (const float*)d_in[20];
    const float* OM   = (const float*)d_in[21];
    const float* OV   = (const float*)d_in[22];
    float* out = (float*)d_out;

    const int N = NN, E = NE;
    const int* src = ei;
    const int* dst = ei + E;

    char* ws = (char*)d_ws;
    size_t off = 0;
    auto alloc = [&](size_t bytes) -> void* {
        void* p = ws + off;
        off += (bytes + 255) & ~(size_t)255;
        return p;
    };
    int*   row_ptr  = (int*)alloc((N + 1) * sizeof(int));
    int*   blocksum = (int*)alloc(256 * sizeof(int));
    int*   rank     = (int*)alloc((size_t)E * sizeof(int));
    // ---- contiguous zero region ----
    char*  zbase    = ws + off;
    int*   deg      = (int*)alloc(N * sizeof(int));
    float* sums     = (float*)alloc(NG * 64 * sizeof(float));
    int*   cnt      = (int*)alloc(NG * sizeof(int));
    size_t zlen     = (ws + off) - zbase;
    // ---- rest ----
    unsigned short* col = (unsigned short*)alloc((size_t)E * sizeof(unsigned short));
    unsigned* xb    = (unsigned*)alloc((size_t)N * 64 * 4);
    unsigned short* ybuf = (unsigned short*)alloc((size_t)N * 128 * 2);
    unsigned short* hbuf = (unsigned short*)alloc((size_t)N * 64 * 2);
    unsigned short* w1t  = (unsigned short*)alloc(49152 * 2);
    unsigned short* w2t  = (unsigned short*)alloc(5 * 64 * 128 * 2);
    float* s1 = (float*)alloc(5 * 128 * sizeof(float));
    float* c1 = (float*)alloc(5 * 128 * sizeof(float));
    float* s2 = (float*)alloc(5 * 64 * sizeof(float));
    float* c2 = (float*)alloc(5 * 64 * sizeof(float));

    const int NB = (N + 255) / 256;
    const int EB = (E + 255) / 256;

    hipMemsetAsync(zbase, 0, zlen, stream);

    PrepArgs p;
    p.w1[0] = w1_0; p.w2[0] = w2_0; p.b1[0] = b1_0; p.ig[0] = ig0; p.ib[0] = ib0;
    p.im[0] = im0; p.iv[0] = iv0; p.b2[0] = b2_0;
    for (int i = 1; i < 5; ++i) {
        p.w1[i] = W1s + (size_t)(i - 1) * 64 * 128;
        p.w2[i] = W2s + (size_t)(i - 1) * 128 * 64;
        p.b1[i] = b1s + (i - 1) * 128;
        p.ig[i] = IG + (i - 1) * 128; p.ib[i] = IB + (i - 1) * 128;
        p.im[i] = IM + (i - 1) * 128; p.iv[i] = IV + (i - 1) * 128;
        p.b2[i] = b2s + (i - 1) * 64;
    }
    p.og = OG; p.ob = OB; p.om = OM; p.ov = OV;
    p.w1t[0] = w1t;
    for (int i = 1; i < 5; ++i) p.w1t[i] = w1t + 16384 + (size_t)(i - 1) * 8192;
    for (int i = 0; i < 5; ++i) {
        p.w2t[i] = w2t + (size_t)i * 8192;
        p.s1[i] = s1 + i * 128; p.c1[i] = c1 + i * 128;
        p.s2[i] = s2 + i * 64;  p.c2[i] = c2 + i * 64;
    }
    prep_kernel<<<5, 256, 0, stream>>>(p);

    // CSR: rank(hist) -> scan -> atomic-free fill
    rank_kernel<<<EB, 256, 0, stream>>>(dst, deg, rank, E);
    scan1_kernel<<<NB, 256, 0, stream>>>(deg, row_ptr, blocksum, N);
    scan2_kernel<<<1, 256, 0, stream>>>(blocksum, NB);
    scan3_kernel<<<NB, 256, 0, stream>>>(row_ptr, blocksum, N);
    fill2_kernel<<<EB, 256, 0, stream>>>(src, dst, rank, row_ptr, col, E);

    xcvt_kernel<<<(N * 64 + 255) / 256, 256, 0, stream>>>(x, xb, N * 64);

    const int MGB = (N + 63) / 64;
    const int ANB = (N + 15) / 16;   // 3125

    // layer 0
    agg_split<64><<<dim3(ANB, 4), 256, 0, stream>>>(xb, row_ptr, col, (unsigned*)ybuf, N);
    mlp_mfma<128><<<MGB, 256, 0, stream>>>(ybuf, hbuf, p.w1t[0], p.w2t[0],
                                           p.s1[0], p.c1[0], p.s2[0], p.c2[0], N);
    // layers 1..4
    for (int i = 1; i < 5; ++i) {
        agg_split<32><<<dim3(ANB, 2), 256, 0, stream>>>((const unsigned*)hbuf, row_ptr, col,
                                                        (unsigned*)ybuf, N);
        mlp_mfma<64><<<MGB, 256, 0, stream>>>(ybuf, hbuf, p.w1t[i], p.w2t[i],
                                              p.s1[i], p.c1[i], p.s2[i], p.c2[i], N);
    }

    pool_kernel<<<NB, 256, 0, stream>>>(hbuf, batch, sums, cnt, N);
    finalize_kernel<<<32, 256, 0, stream>>>(sums, cnt, out);
}

// Round 13
// 476.978 us; speedup vs baseline: 1.9541x; 1.0003x over previous
//
#include <hip/hip_runtime.h>
#include <stdint.h>

#define NN 50000
#define NE 800000
#define NG 128
#define BN_EPS 1e-5f

typedef __attribute__((ext_vector_type(8))) __bf16 bf16x8;
typedef __attribute__((ext_vector_type(8))) unsigned short ushort8;
typedef __attribute__((ext_vector_type(4))) float floatx4;

__device__ inline unsigned short f2bf(float f) {
    union { float f; unsigned u; } x; x.f = f;
    unsigned u = x.u;
    return (unsigned short)((u + 0x7fffu + ((u >> 16) & 1u)) >> 16);
}
__device__ inline float bflo(unsigned u) {
    union { unsigned u; float f; } x; x.u = u << 16; return x.f;
}
__device__ inline float bfhi(unsigned u) {
    union { unsigned u; float f; } x; x.u = u & 0xffff0000u; return x.f;
}
__device__ inline unsigned pack_bf2(float a, float b) {
    union { struct { __bf16 x, y; } s; unsigned u; } t;
    t.s.x = (__bf16)a; t.s.y = (__bf16)b; return t.u;
}
__device__ inline bf16x8 as_bf(ushort8 u) {
    union { ushort8 u; bf16x8 b; } x; x.u = u; return x.b;
}

// ---------------- CSR build ----------------

__global__ void rank_kernel(const int* __restrict__ dst, int* __restrict__ deg,
                            int* __restrict__ rank, int E) {
    int e = blockIdx.x * 256 + threadIdx.x;
    if (e < E) rank[e] = atomicAdd(&deg[dst[e]], 1);
}

__global__ void scan1_kernel(const int* __restrict__ deg, int* __restrict__ row_ptr,
                             int* __restrict__ blocksum, int n) {
    __shared__ int s[256];
    int i = blockIdx.x * 256 + threadIdx.x;
    int v = (i < n) ? deg[i] : 0;
    s[threadIdx.x] = v;
    __syncthreads();
    for (int off = 1; off < 256; off <<= 1) {
        int t = (threadIdx.x >= off) ? s[threadIdx.x - off] : 0;
        __syncthreads();
        s[threadIdx.x] += t;
        __syncthreads();
    }
    if (i < n) row_ptr[i + 1] = s[threadIdx.x];
    if (threadIdx.x == 255) blocksum[blockIdx.x] = s[255];
}

__global__ void scan2_kernel(int* __restrict__ blocksum, int nb) {
    __shared__ int s[256];
    int v = (threadIdx.x < nb) ? blocksum[threadIdx.x] : 0;
    s[threadIdx.x] = v;
    __syncthreads();
    for (int off = 1; off < 256; off <<= 1) {
        int t = (threadIdx.x >= off) ? s[threadIdx.x - off] : 0;
        __syncthreads();
        s[threadIdx.x] += t;
        __syncthreads();
    }
    if (threadIdx.x < nb) blocksum[threadIdx.x] = s[threadIdx.x] - v;
}

__global__ void scan3_kernel(int* __restrict__ row_ptr, const int* __restrict__ blocksum, int n) {
    int i = blockIdx.x * 256 + threadIdx.x;
    if (i < n) row_ptr[i + 1] += blocksum[blockIdx.x];
    if (i == 0) row_ptr[0] = 0;
}

__global__ void fill2_kernel(const int* __restrict__ src, const int* __restrict__ dst,
                             const int* __restrict__ rank, const int* __restrict__ row_ptr,
                             unsigned short* __restrict__ col, int E) {
    int e = blockIdx.x * 256 + threadIdx.x;
    if (e < E) {
        int d = dst[e];
        col[row_ptr[d] + rank[e]] = (unsigned short)src[e];
    }
}

// ---------------- weight prep ----------------

struct PrepArgs {
    const float* w1[5]; const float* w2[5];
    const float* b1[5]; const float* ig[5]; const float* ib[5];
    const float* im[5]; const float* iv[5]; const float* b2[5];
    const float* og; const float* ob; const float* om; const float* ov;
    unsigned short* w1t[5]; unsigned short* w2t[5];
    float* s1[5]; float* c1[5]; float* s2[5]; float* c2[5];
};

__global__ void prep_kernel(PrepArgs p) {
    int layer = blockIdx.x;
    int K = (layer == 0) ? 128 : 64;
    int kshift = (layer == 0) ? 7 : 6;
    const float* w1 = p.w1[layer];
    unsigned short* w1t = p.w1t[layer];
    for (int idx = threadIdx.x; idx < 128 * K; idx += blockDim.x) {
        int c = idx >> kshift, k = idx & (K - 1);
        w1t[idx] = f2bf(w1[k * 128 + c]);
    }
    const float* w2 = p.w2[layer];
    unsigned short* w2t = p.w2t[layer];
    for (int idx = threadIdx.x; idx < 64 * 128; idx += blockDim.x) {
        int c = idx >> 7, k = idx & 127;
        w2t[idx] = f2bf(w2[k * 64 + c]);
    }
    if (threadIdx.x < 128) {
        int ch = threadIdx.x;
        float s = p.ig[layer][ch] * rsqrtf(p.iv[layer][ch] + BN_EPS);
        p.s1[layer][ch] = s;
        p.c1[layer][ch] = (p.b1[layer][ch] - p.im[layer][ch]) * s + p.ib[layer][ch];
        if (ch < 64) {
            float s2v = p.og[layer * 64 + ch] * rsqrtf(p.ov[layer * 64 + ch] + BN_EPS);
            p.s2[layer][ch] = s2v;
            p.c2[layer][ch] = (p.b2[layer][ch] - p.om[layer * 64 + ch]) * s2v + p.ob[layer * 64 + ch];
        }
    }
}

// ---------------- x fp32 -> bf16 ----------------

__global__ void xcvt_kernel(const float* __restrict__ x, unsigned* __restrict__ xb, int npair) {
    int i = blockIdx.x * 256 + threadIdx.x;
    if (i < npair) {
        float2 v = ((const float2*)x)[i];
        xb[i] = pack_bf2(v.x, v.y);
    }
}

// ---------------- aggregation: XCD-pinned channel slices ----------------
// DW dwords per row, NSLICE 64B slices. Each slice is served ONLY by blocks on
// its XCD group (xcd = blockIdx.x % 8, XPS = 8/NSLICE xcds per slice), so each
// XCD's L2 holds a single 3.2 MB slice table -> gather becomes L2-resident.

template <int DW, int NSLICE>
__global__ void agg_xcd(const unsigned* __restrict__ hr, const int* __restrict__ rp,
                        const unsigned short* __restrict__ col, unsigned* __restrict__ y, int n) {
    constexpr int XPS = 8 / NSLICE;
    int b = blockIdx.x;
    int lane8 = b & 7;
    int slice = lane8 / XPS;
    int k = (b >> 3) * XPS + (lane8 & (XPS - 1));   // node-group id
    int node = k * 16 + (threadIdx.x >> 4);
    int l = threadIdx.x & 15;
    if (node >= n) return;
    const unsigned* base = hr + slice * 16 + l;
    unsigned u = base[(size_t)node * DW];
    float a0 = bflo(u), a1 = bfhi(u);
    int beg = rp[node], end = rp[node + 1];
    int e = beg;
    for (; e + 4 <= end; e += 4) {
        unsigned v0 = base[(size_t)col[e]     * DW];
        unsigned v1 = base[(size_t)col[e + 1] * DW];
        unsigned v2 = base[(size_t)col[e + 2] * DW];
        unsigned v3 = base[(size_t)col[e + 3] * DW];
        a0 += bflo(v0); a1 += bfhi(v0);
        a0 += bflo(v1); a1 += bfhi(v1);
        a0 += bflo(v2); a1 += bfhi(v2);
        a0 += bflo(v3); a1 += bfhi(v3);
    }
    for (; e < end; ++e) {
        unsigned v = base[(size_t)col[e] * DW];
        a0 += bflo(v); a1 += bfhi(v);
    }
    y[(size_t)node * DW + slice * 16 + l] = pack_bf2(a0, a1);
}

// ---------------- fused MLP via MFMA ----------------

template <int K>
__launch_bounds__(256, 3)
__global__ void mlp_mfma(const unsigned short* __restrict__ yb, unsigned short* __restrict__ hb,
                         const unsigned short* __restrict__ w1t,  // [128][K] bf16
                         const unsigned short* __restrict__ w2t,  // [64][128] bf16
                         const float* __restrict__ s1, const float* __restrict__ c1,
                         const float* __restrict__ s2, const float* __restrict__ c2,
                         int n) {
    __shared__ float zl[64 * 132];
    const int tid = threadIdx.x;
    const int w = tid >> 6;
    const int l = tid & 63;
    const int l15 = l & 15, lg = l >> 4;
    const int node0 = blockIdx.x * 64;

    // ---- GEMM1: Z[64x128] = Y[64xK] @ W1[Kx128]
    const int arow = node0 + w * 16 + l15;
    const int arow_c = min(arow, n - 1);
    bf16x8 afr[K / 32];
#pragma unroll
    for (int ks = 0; ks < K / 32; ++ks)
        afr[ks] = as_bf(*(const ushort8*)(yb + (size_t)arow_c * K + ks * 32 + lg * 8));

#pragma unroll
    for (int cc = 0; cc < 8; ++cc) {
        floatx4 acc = {0.f, 0.f, 0.f, 0.f};
#pragma unroll
        for (int ks = 0; ks < K / 32; ++ks) {
            bf16x8 bfr = as_bf(*(const ushort8*)(w1t + (size_t)(cc * 16 + l15) * K + ks * 32 + lg * 8));
            acc = __builtin_amdgcn_mfma_f32_16x16x32_bf16(afr[ks], bfr, acc, 0, 0, 0);
        }
        int ch = cc * 16 + l15;
        float s = s1[ch], c = c1[ch];
#pragma unroll
        for (int r = 0; r < 4; ++r) {
            int row = w * 16 + lg * 4 + r;
            zl[row * 132 + ch] = fmaxf(acc[r] * s + c, 0.f);
        }
    }
    __syncthreads();

    // ---- GEMM2: H[64x64] = Zr[64x128] @ W2[128x64]
    floatx4 acc2[4];
#pragma unroll
    for (int ct = 0; ct < 4; ++ct) acc2[ct] = (floatx4){0.f, 0.f, 0.f, 0.f};

#pragma unroll
    for (int ks = 0; ks < 4; ++ks) {
        const float* zp = &zl[(w * 16 + l15) * 132 + ks * 32 + lg * 8];
        float4 za = *(const float4*)zp;
        float4 zb = *(const float4*)(zp + 4);
        bf16x8 a2;
        a2[0] = (__bf16)za.x; a2[1] = (__bf16)za.y; a2[2] = (__bf16)za.z; a2[3] = (__bf16)za.w;
        a2[4] = (__bf16)zb.x; a2[5] = (__bf16)zb.y; a2[6] = (__bf16)zb.z; a2[7] = (__bf16)zb.w;
#pragma unroll
        for (int ct = 0; ct < 4; ++ct) {
            bf16x8 b2 = as_bf(*(const ushort8*)(w2t + (size_t)(ct * 16 + l15) * 128 + ks * 32 + lg * 8));
            acc2[ct] = __builtin_amdgcn_mfma_f32_16x16x32_bf16(a2, b2, acc2[ct], 0, 0, 0);
        }
    }
    __syncthreads();

    // ---- BN2 + ReLU -> per-wave H region, then coalesced bf16 store
    float* Hp = zl + w * 2112;
#pragma unroll
    for (int ct = 0; ct < 4; ++ct) {
        int ch = ct * 16 + l15;
        float s = s2[ch], c = c2[ch];
#pragma unroll
        for (int r = 0; r < 4; ++r)
            Hp[(lg * 4 + r) * 68 + ch] = fmaxf(acc2[ct][r] * s + c, 0.f);
    }
    __syncthreads();

    int nr = l >> 2, ch0 = (l & 3) * 16;
    int node = node0 + w * 16 + nr;
    if (node < n) {
        const float* q = Hp + nr * 68 + ch0;
        ushort8 u0, u1;
#pragma unroll
        for (int j = 0; j < 8; ++j) { union { __bf16 b; unsigned short s; } t; t.b = (__bf16)q[j]; u0[j] = t.s; }
#pragma unroll
        for (int j = 0; j < 8; ++j) { union { __bf16 b; unsigned short s; } t; t.b = (__bf16)q[8 + j]; u1[j] = t.s; }
        *(ushort8*)(hb + (size_t)node * 64 + ch0) = u0;
        *(ushort8*)(hb + (size_t)node * 64 + ch0 + 8) = u1;
    }
}

// ---------------- pooling (batch sorted): half-wave per 32 nodes ----------------

__global__ void pool_kernel(const unsigned short* __restrict__ h, const int* __restrict__ batch,
                            float* __restrict__ sums, int* __restrict__ cnt, int n) {
    int hw = (blockIdx.x * 256 + threadIdx.x) >> 5;
    int l = threadIdx.x & 31;
    int n0 = hw * 32;
    if (n0 >= n) return;
    int n1 = min(n0 + 32, n);
    const unsigned* hr = (const unsigned*)h;
    float a0 = 0.f, a1 = 0.f; int c = 0;
    int g_cur = batch[n0];
    for (int i = n0; i < n1; ++i) {
        int g = batch[i];
        if (g != g_cur) {
            atomicAdd(&sums[g_cur * 64 + 2 * l], a0);
            atomicAdd(&sums[g_cur * 64 + 2 * l + 1], a1);
            if (l == 0) atomicAdd(&cnt[g_cur], c);
            a0 = a1 = 0.f; c = 0; g_cur = g;
        }
        unsigned u = hr[(size_t)i * 32 + l];
        a0 += bflo(u); a1 += bfhi(u);
        c++;
    }
    atomicAdd(&sums[g_cur * 64 + 2 * l], a0);
    atomicAdd(&sums[g_cur * 64 + 2 * l + 1], a1);
    if (l == 0) atomicAdd(&cnt[g_cur], c);
}

__global__ void finalize_kernel(const float* __restrict__ sums, const int* __restrict__ cnt,
                                float* __restrict__ out) {
    int i = blockIdx.x * 256 + threadIdx.x;
    if (i < NG * 64) {
        float c = (float)cnt[i >> 6];
        out[i] = sums[i] / fmaxf(c, 1.f);
    }
}

// ---------------- launcher ----------------

extern "C" void kernel_launch(void* const* d_in, const int* in_sizes, int n_in,
                              void* d_out, int out_size, void* d_ws, size_t ws_size,
                              hipStream_t stream) {
    const float* x    = (const float*)d_in[0];
    const int*  ei    = (const int*)d_in[1];
    const int*  batch = (const int*)d_in[2];
    const float* w1_0 = (const float*)d_in[3];
    const float* b1_0 = (const float*)d_in[4];
    const float* ig0  = (const float*)d_in[5];
    const float* ib0  = (const float*)d_in[6];
    const float* im0  = (const float*)d_in[7];
    const float* iv0  = (const float*)d_in[8];
    const float* w2_0 = (const float*)d_in[9];
    const float* b2_0 = (const float*)d_in[10];
    const float* W1s  = (const float*)d_in[11];
    const float* b1s  = (const float*)d_in[12];
    const float* IG   = (const float*)d_in[13];
    const float* IB   = (const float*)d_in[14];
    const float* IM   = (const float*)d_in[15];
    const float* IV   = (const float*)d_in[16];
    const float* W2s  = (const float*)d_in[17];
    const float* b2s  = (const float*)d_in[18];
    const float* OG   = (const float*)d_in[19];
    const float* OB   = (const float*)d_in[20];
    const float* OM   = (const float*)d_in[21];
    const float* OV   = (const float*)d_in[22];
    float* out = (float*)d_out;

    const int N = NN, E = NE;
    const int* src = ei;
    const int* dst = ei + E;

    char* ws = (char*)d_ws;
    size_t off = 0;
    auto alloc = [&](size_t bytes) -> void* {
        void* p = ws + off;
        off += (bytes + 255) & ~(size_t)255;
        return p;
    };
    int*   row_ptr  = (int*)alloc((N + 1) * sizeof(int));
    int*   blocksum = (int*)alloc(256 * sizeof(int));
    int*   rank     = (int*)alloc((size_t)E * sizeof(int));
    // ---- contiguous zero region ----
    char*  zbase    = ws + off;
    int*   deg      = (int*)alloc(N * sizeof(int));
    float* sums     = (float*)alloc(NG * 64 * sizeof(float));
    int*   cnt      = (int*)alloc(NG * sizeof(int));
    size_t zlen     = (ws + off) - zbase;
    // ---- rest ----
    unsigned short* col = (unsigned short*)alloc((size_t)E * sizeof(unsigned short));
    unsigned* xb    = (unsigned*)alloc((size_t)N * 64 * 4);
    unsigned short* ybuf = (unsigned short*)alloc((size_t)N * 128 * 2);
    unsigned short* hbuf = (unsigned short*)alloc((size_t)N * 64 * 2);
    unsigned short* w1t  = (unsigned short*)alloc(49152 * 2);
    unsigned short* w2t  = (unsigned short*)alloc(5 * 64 * 128 * 2);
    float* s1 = (float*)alloc(5 * 128 * sizeof(float));
    float* c1 = (float*)alloc(5 * 128 * sizeof(float));
    float* s2 = (float*)alloc(5 * 64 * sizeof(float));
    float* c2 = (float*)alloc(5 * 64 * sizeof(float));

    const int NB = (N + 255) / 256;
    const int EB = (E + 255) / 256;

    hipMemsetAsync(zbase, 0, zlen, stream);

    PrepArgs p;
    p.w1[0] = w1_0; p.w2[0] = w2_0; p.b1[0] = b1_0; p.ig[0] = ig0; p.ib[0] = ib0;
    p.im[0] = im0; p.iv[0] = iv0; p.b2[0] = b2_0;
    for (int i = 1; i < 5; ++i) {
        p.w1[i] = W1s + (size_t)(i - 1) * 64 * 128;
        p.w2[i] = W2s + (size_t)(i - 1) * 128 * 64;
        p.b1[i] = b1s + (i - 1) * 128;
        p.ig[i] = IG + (i - 1) * 128; p.ib[i] = IB + (i - 1) * 128;
        p.im[i] = IM + (i - 1) * 128; p.iv[i] = IV + (i - 1) * 128;
        p.b2[i] = b2s + (i - 1) * 64;
    }
    p.og = OG; p.ob = OB; p.om = OM; p.ov = OV;
    p.w1t[0] = w1t;
    for (int i = 1; i < 5; ++i) p.w1t[i] = w1t + 16384 + (size_t)(i - 1) * 8192;
    for (int i = 0; i < 5; ++i) {
        p.w2t[i] = w2t + (size_t)i * 8192;
        p.s1[i] = s1 + i * 128; p.c1[i] = c1 + i * 128;
        p.s2[i] = s2 + i * 64;  p.c2[i] = c2 + i * 64;
    }
    prep_kernel<<<5, 256, 0, stream>>>(p);

    // CSR: rank(hist) -> scan -> atomic-free fill
    rank_kernel<<<EB, 256, 0, stream>>>(dst, deg, rank, E);
    scan1_kernel<<<NB, 256, 0, stream>>>(deg, row_ptr, blocksum, N);
    scan2_kernel<<<1, 256, 0, stream>>>(blocksum, NB);
    scan3_kernel<<<NB, 256, 0, stream>>>(row_ptr, blocksum, N);
    fill2_kernel<<<EB, 256, 0, stream>>>(src, dst, rank, row_ptr, col, E);

    xcvt_kernel<<<(N * 64 + 255) / 256, 256, 0, stream>>>(x, xb, N * 64);

    const int MGB = (N + 63) / 64;
    const int NGRP = (N + 15) / 16;                 // 3125 node-groups
    const int AG0 = ((NGRP + 1) / 2) * 8;           // NSLICE=4, XPS=2 -> 12504
    const int AG1 = ((NGRP + 3) / 4) * 8;           // NSLICE=2, XPS=4 -> 6256

    // layer 0
    agg_xcd<64, 4><<<AG0, 256, 0, stream>>>(xb, row_ptr, col, (unsigned*)ybuf, N);
    mlp_mfma<128><<<MGB, 256, 0, stream>>>(ybuf, hbuf, p.w1t[0], p.w2t[0],
                                           p.s1[0], p.c1[0], p.s2[0], p.c2[0], N);
    // layers 1..4
    for (int i = 1; i < 5; ++i) {
        agg_xcd<32, 2><<<AG1, 256, 0, stream>>>((const unsigned*)hbuf, row_ptr, col,
                                                (unsigned*)ybuf, N);
        mlp_mfma<64><<<MGB, 256, 0, stream>>>(ybuf, hbuf, p.w1t[i], p.w2t[i],
                                              p.s1[i], p.c1[i], p.s2[i], p.c2[i], N);
    }

    pool_kernel<<<NB, 256, 0, stream>>>(hbuf, batch, sums, cnt, N);
    finalize_kernel<<<32, 256, 0, stream>>>(sums, cnt, out);
}

// Round 15
// 427.941 us; speedup vs baseline: 2.1781x; 1.1146x over previous
//
#include <hip/hip_runtime.h>
#include <stdint.h>

#define NN 50000
#define NE 800000
#define NG 128
#define BN_EPS 1e-5f

typedef __attribute__((ext_vector_type(8))) __bf16 bf16x8;
typedef __attribute__((ext_vector_type(8))) unsigned short ushort8;
typedef __attribute__((ext_vector_type(4))) float floatx4;

__device__ inline unsigned short f2bf(float f) {
    union { float f; unsigned u; } x; x.f = f;
    unsigned u = x.u;
    return (unsigned short)((u + 0x7fffu + ((u >> 16) & 1u)) >> 16);
}
__device__ inline float bflo(unsigned u) {
    union { unsigned u; float f; } x; x.u = u << 16; return x.f;
}
__device__ inline float bfhi(unsigned u) {
    union { unsigned u; float f; } x; x.u = u & 0xffff0000u; return x.f;
}
__device__ inline unsigned pack_bf2(float a, float b) {
    union { struct { __bf16 x, y; } s; unsigned u; } t;
    t.s.x = (__bf16)a; t.s.y = (__bf16)b; return t.u;
}
__device__ inline bf16x8 as_bf(ushort8 u) {
    union { ushort8 u; bf16x8 b; } x; x.u = u; return x.b;
}

// ---------------- CSR build ----------------

__global__ void rank_kernel(const int* __restrict__ dst, int* __restrict__ deg,
                            int* __restrict__ rank, int E) {
    int e = blockIdx.x * 256 + threadIdx.x;
    if (e < E) rank[e] = atomicAdd(&deg[dst[e]], 1);
}

__global__ void scan1_kernel(const int* __restrict__ deg, int* __restrict__ row_ptr,
                             int* __restrict__ blocksum, int n) {
    __shared__ int s[256];
    int i = blockIdx.x * 256 + threadIdx.x;
    int v = (i < n) ? deg[i] : 0;
    s[threadIdx.x] = v;
    __syncthreads();
    for (int off = 1; off < 256; off <<= 1) {
        int t = (threadIdx.x >= off) ? s[threadIdx.x - off] : 0;
        __syncthreads();
        s[threadIdx.x] += t;
        __syncthreads();
    }
    if (i < n) row_ptr[i + 1] = s[threadIdx.x];
    if (threadIdx.x == 255) blocksum[blockIdx.x] = s[255];
}

__global__ void scan2_kernel(int* __restrict__ blocksum, int nb) {
    __shared__ int s[256];
    int v = (threadIdx.x < nb) ? blocksum[threadIdx.x] : 0;
    s[threadIdx.x] = v;
    __syncthreads();
    for (int off = 1; off < 256; off <<= 1) {
        int t = (threadIdx.x >= off) ? s[threadIdx.x - off] : 0;
        __syncthreads();
        s[threadIdx.x] += t;
        __syncthreads();
    }
    if (threadIdx.x < nb) blocksum[threadIdx.x] = s[threadIdx.x] - v;
}

__global__ void scan3_kernel(int* __restrict__ row_ptr, const int* __restrict__ blocksum, int n) {
    int i = blockIdx.x * 256 + threadIdx.x;
    if (i < n) row_ptr[i + 1] += blocksum[blockIdx.x];
    if (i == 0) row_ptr[0] = 0;
}

__global__ void fill2_kernel(const int* __restrict__ src, const int* __restrict__ dst,
                             const int* __restrict__ rank, const int* __restrict__ row_ptr,
                             unsigned short* __restrict__ col, int E) {
    int e = blockIdx.x * 256 + threadIdx.x;
    if (e < E) {
        int d = dst[e];
        col[row_ptr[d] + rank[e]] = (unsigned short)src[e];
    }
}

// ---------------- weight prep ----------------

struct PrepArgs {
    const float* w1[5]; const float* w2[5];
    const float* b1[5]; const float* ig[5]; const float* ib[5];
    const float* im[5]; const float* iv[5]; const float* b2[5];
    const float* og; const float* ob; const float* om; const float* ov;
    unsigned short* w1t[5]; unsigned short* w2t[5];
    float* s1[5]; float* c1[5]; float* s2[5]; float* c2[5];
};

__global__ void prep_kernel(PrepArgs p) {
    int layer = blockIdx.x;
    int K = (layer == 0) ? 128 : 64;
    int kshift = (layer == 0) ? 7 : 6;
    const float* w1 = p.w1[layer];
    unsigned short* w1t = p.w1t[layer];
    for (int idx = threadIdx.x; idx < 128 * K; idx += blockDim.x) {
        int c = idx >> kshift, k = idx & (K - 1);
        w1t[idx] = f2bf(w1[k * 128 + c]);
    }
    const float* w2 = p.w2[layer];
    unsigned short* w2t = p.w2t[layer];
    for (int idx = threadIdx.x; idx < 64 * 128; idx += blockDim.x) {
        int c = idx >> 7, k = idx & 127;
        w2t[idx] = f2bf(w2[k * 64 + c]);
    }
    if (threadIdx.x < 128) {
        int ch = threadIdx.x;
        float s = p.ig[layer][ch] * rsqrtf(p.iv[layer][ch] + BN_EPS);
        p.s1[layer][ch] = s;
        p.c1[layer][ch] = (p.b1[layer][ch] - p.im[layer][ch]) * s + p.ib[layer][ch];
        if (ch < 64) {
            float s2v = p.og[layer * 64 + ch] * rsqrtf(p.ov[layer * 64 + ch] + BN_EPS);
            p.s2[layer][ch] = s2v;
            p.c2[layer][ch] = (p.b2[layer][ch] - p.om[layer * 64 + ch]) * s2v + p.ob[layer * 64 + ch];
        }
    }
}

// ---------------- x fp32 -> bf16 ----------------

__global__ void xcvt_kernel(const float* __restrict__ x, unsigned* __restrict__ xb, int npair) {
    int i = blockIdx.x * 256 + threadIdx.x;
    if (i < npair) {
        float2 v = ((const float2*)x)[i];
        xb[i] = pack_bf2(v.x, v.y);
    }
}

// ---------------- aggregation: full-row wide gathers ----------------
// 16-lane group per node; the group reads a FULL feature row per edge in one
// instruction (DW=64: uint4/lane = 256B; DW=32: uint2/lane = 128B). 4-edge
// unroll for bytes-in-flight. Rows are 16 chunks; lane l owns chunk l.

__global__ void agg_wide128(const uint4* __restrict__ hr, const int* __restrict__ rp,
                            const unsigned short* __restrict__ col, uint4* __restrict__ y, int n) {
    int node = blockIdx.x * 16 + (threadIdx.x >> 4);
    int l = threadIdx.x & 15;
    if (node >= n) return;
    const uint4* base = hr + l;
    uint4 u = base[(size_t)node * 16];
    float a0 = bflo(u.x), a1 = bfhi(u.x), a2 = bflo(u.y), a3 = bfhi(u.y);
    float a4 = bflo(u.z), a5 = bfhi(u.z), a6 = bflo(u.w), a7 = bfhi(u.w);
    int beg = rp[node], end = rp[node + 1];
    int e = beg;
    for (; e + 4 <= end; e += 4) {
        uint4 v0 = base[(size_t)col[e]     * 16];
        uint4 v1 = base[(size_t)col[e + 1] * 16];
        uint4 v2 = base[(size_t)col[e + 2] * 16];
        uint4 v3 = base[(size_t)col[e + 3] * 16];
        a0 += bflo(v0.x); a1 += bfhi(v0.x); a2 += bflo(v0.y); a3 += bfhi(v0.y);
        a4 += bflo(v0.z); a5 += bfhi(v0.z); a6 += bflo(v0.w); a7 += bfhi(v0.w);
        a0 += bflo(v1.x); a1 += bfhi(v1.x); a2 += bflo(v1.y); a3 += bfhi(v1.y);
        a4 += bflo(v1.z); a5 += bfhi(v1.z); a6 += bflo(v1.w); a7 += bfhi(v1.w);
        a0 += bflo(v2.x); a1 += bfhi(v2.x); a2 += bflo(v2.y); a3 += bfhi(v2.y);
        a4 += bflo(v2.z); a5 += bfhi(v2.z); a6 += bflo(v2.w); a7 += bfhi(v2.w);
        a0 += bflo(v3.x); a1 += bfhi(v3.x); a2 += bflo(v3.y); a3 += bfhi(v3.y);
        a4 += bflo(v3.z); a5 += bfhi(v3.z); a6 += bflo(v3.w); a7 += bfhi(v3.w);
    }
    for (; e < end; ++e) {
        uint4 v = base[(size_t)col[e] * 16];
        a0 += bflo(v.x); a1 += bfhi(v.x); a2 += bflo(v.y); a3 += bfhi(v.y);
        a4 += bflo(v.z); a5 += bfhi(v.z); a6 += bflo(v.w); a7 += bfhi(v.w);
    }
    uint4 o;
    o.x = pack_bf2(a0, a1); o.y = pack_bf2(a2, a3);
    o.z = pack_bf2(a4, a5); o.w = pack_bf2(a6, a7);
    (y + l)[(size_t)node * 16] = o;
}

__global__ void agg_wide64(const uint2* __restrict__ hr, const int* __restrict__ rp,
                           const unsigned short* __restrict__ col, uint2* __restrict__ y, int n) {
    int node = blockIdx.x * 16 + (threadIdx.x >> 4);
    int l = threadIdx.x & 15;
    if (node >= n) return;
    const uint2* base = hr + l;
    uint2 u = base[(size_t)node * 16];
    float a0 = bflo(u.x), a1 = bfhi(u.x), a2 = bflo(u.y), a3 = bfhi(u.y);
    int beg = rp[node], end = rp[node + 1];
    int e = beg;
    for (; e + 4 <= end; e += 4) {
        uint2 v0 = base[(size_t)col[e]     * 16];
        uint2 v1 = base[(size_t)col[e + 1] * 16];
        uint2 v2 = base[(size_t)col[e + 2] * 16];
        uint2 v3 = base[(size_t)col[e + 3] * 16];
        a0 += bflo(v0.x); a1 += bfhi(v0.x); a2 += bflo(v0.y); a3 += bfhi(v0.y);
        a0 += bflo(v1.x); a1 += bfhi(v1.x); a2 += bflo(v1.y); a3 += bfhi(v1.y);
        a0 += bflo(v2.x); a1 += bfhi(v2.x); a2 += bflo(v2.y); a3 += bfhi(v2.y);
        a0 += bflo(v3.x); a1 += bfhi(v3.x); a2 += bflo(v3.y); a3 += bfhi(v3.y);
    }
    for (; e < end; ++e) {
        uint2 v = base[(size_t)col[e] * 16];
        a0 += bflo(v.x); a1 += bfhi(v.x); a2 += bflo(v.y); a3 += bfhi(v.y);
    }
    uint2 o;
    o.x = pack_bf2(a0, a1); o.y = pack_bf2(a2, a3);
    (y + l)[(size_t)node * 16] = o;
}

// ---------------- fused MLP via MFMA ----------------

template <int K>
__launch_bounds__(256, 3)
__global__ void mlp_mfma(const unsigned short* __restrict__ yb, unsigned short* __restrict__ hb,
                         const unsigned short* __restrict__ w1t,  // [128][K] bf16
                         const unsigned short* __restrict__ w2t,  // [64][128] bf16
                         const float* __restrict__ s1, const float* __restrict__ c1,
                         const float* __restrict__ s2, const float* __restrict__ c2,
                         int n) {
    __shared__ float zl[64 * 132];
    const int tid = threadIdx.x;
    const int w = tid >> 6;
    const int l = tid & 63;
    const int l15 = l & 15, lg = l >> 4;
    const int node0 = blockIdx.x * 64;

    // ---- GEMM1: Z[64x128] = Y[64xK] @ W1[Kx128]
    const int arow = node0 + w * 16 + l15;
    const int arow_c = min(arow, n - 1);
    bf16x8 afr[K / 32];
#pragma unroll
    for (int ks = 0; ks < K / 32; ++ks)
        afr[ks] = as_bf(*(const ushort8*)(yb + (size_t)arow_c * K + ks * 32 + lg * 8));

#pragma unroll
    for (int cc = 0; cc < 8; ++cc) {
        floatx4 acc = {0.f, 0.f, 0.f, 0.f};
#pragma unroll
        for (int ks = 0; ks < K / 32; ++ks) {
            bf16x8 bfr = as_bf(*(const ushort8*)(w1t + (size_t)(cc * 16 + l15) * K + ks * 32 + lg * 8));
            acc = __builtin_amdgcn_mfma_f32_16x16x32_bf16(afr[ks], bfr, acc, 0, 0, 0);
        }
        int ch = cc * 16 + l15;
        float s = s1[ch], c = c1[ch];
#pragma unroll
        for (int r = 0; r < 4; ++r) {
            int row = w * 16 + lg * 4 + r;
            zl[row * 132 + ch] = fmaxf(acc[r] * s + c, 0.f);
        }
    }
    __syncthreads();

    // ---- GEMM2: H[64x64] = Zr[64x128] @ W2[128x64]
    floatx4 acc2[4];
#pragma unroll
    for (int ct = 0; ct < 4; ++ct) acc2[ct] = (floatx4){0.f, 0.f, 0.f, 0.f};

#pragma unroll
    for (int ks = 0; ks < 4; ++ks) {
        const float* zp = &zl[(w * 16 + l15) * 132 + ks * 32 + lg * 8];
        float4 za = *(const float4*)zp;
        float4 zb = *(const float4*)(zp + 4);
        bf16x8 a2;
        a2[0] = (__bf16)za.x; a2[1] = (__bf16)za.y; a2[2] = (__bf16)za.z; a2[3] = (__bf16)za.w;
        a2[4] = (__bf16)zb.x; a2[5] = (__bf16)zb.y; a2[6] = (__bf16)zb.z; a2[7] = (__bf16)zb.w;
#pragma unroll
        for (int ct = 0; ct < 4; ++ct) {
            bf16x8 b2 = as_bf(*(const ushort8*)(w2t + (size_t)(ct * 16 + l15) * 128 + ks * 32 + lg * 8));
            acc2[ct] = __builtin_amdgcn_mfma_f32_16x16x32_bf16(a2, b2, acc2[ct], 0, 0, 0);
        }
    }
    __syncthreads();

    // ---- BN2 + ReLU -> per-wave H region, then coalesced bf16 store
    float* Hp = zl + w * 2112;
#pragma unroll
    for (int ct = 0; ct < 4; ++ct) {
        int ch = ct * 16 + l15;
        float s = s2[ch], c = c2[ch];
#pragma unroll
        for (int r = 0; r < 4; ++r)
            Hp[(lg * 4 + r) * 68 + ch] = fmaxf(acc2[ct][r] * s + c, 0.f);
    }
    __syncthreads();

    int nr = l >> 2, ch0 = (l & 3) * 16;
    int node = node0 + w * 16 + nr;
    if (node < n) {
        const float* q = Hp + nr * 68 + ch0;
        ushort8 u0, u1;
#pragma unroll
        for (int j = 0; j < 8; ++j) { union { __bf16 b; unsigned short s; } t; t.b = (__bf16)q[j]; u0[j] = t.s; }
#pragma unroll
        for (int j = 0; j < 8; ++j) { union { __bf16 b; unsigned short s; } t; t.b = (__bf16)q[8 + j]; u1[j] = t.s; }
        *(ushort8*)(hb + (size_t)node * 64 + ch0) = u0;
        *(ushort8*)(hb + (size_t)node * 64 + ch0 + 8) = u1;
    }
}

// ---------------- pooling (batch sorted): half-wave per 32 nodes ----------------

__global__ void pool_kernel(const unsigned short* __restrict__ h, const int* __restrict__ batch,
                            float* __restrict__ sums, int* __restrict__ cnt, int n) {
    int hw = (blockIdx.x * 256 + threadIdx.x) >> 5;
    int l = threadIdx.x & 31;
    int n0 = hw * 32;
    if (n0 >= n) return;
    int n1 = min(n0 + 32, n);
    const unsigned* hr = (const unsigned*)h;
    float a0 = 0.f, a1 = 0.f; int c = 0;
    int g_cur = batch[n0];
    for (int i = n0; i < n1; ++i) {
        int g = batch[i];
        if (g != g_cur) {
            atomicAdd(&sums[g_cur * 64 + 2 * l], a0);
            atomicAdd(&sums[g_cur * 64 + 2 * l + 1], a1);
            if (l == 0) atomicAdd(&cnt[g_cur], c);
            a0 = a1 = 0.f; c = 0; g_cur = g;
        }
        unsigned u = hr[(size_t)i * 32 + l];
        a0 += bflo(u); a1 += bfhi(u);
        c++;
    }
    atomicAdd(&sums[g_cur * 64 + 2 * l], a0);
    atomicAdd(&sums[g_cur * 64 + 2 * l + 1], a1);
    if (l == 0) atomicAdd(&cnt[g_cur], c);
}

__global__ void finalize_kernel(const float* __restrict__ sums, const int* __restrict__ cnt,
                                float* __restrict__ out) {
    int i = blockIdx.x * 256 + threadIdx.x;
    if (i < NG * 64) {
        float c = (float)cnt[i >> 6];
        out[i] = sums[i] / fmaxf(c, 1.f);
    }
}

// ---------------- launcher ----------------

extern "C" void kernel_launch(void* const* d_in, const int* in_sizes, int n_in,
                              void* d_out, int out_size, void* d_ws, size_t ws_size,
                              hipStream_t stream) {
    const float* x    = (const float*)d_in[0];
    const int*  ei    = (const int*)d_in[1];
    const int*  batch = (const int*)d_in[2];
    const float* w1_0 = (const float*)d_in[3];
    const float* b1_0 = (const float*)d_in[4];
    const float* ig0  = (const float*)d_in[5];
    const float* ib0  = (const float*)d_in[6];
    const float* im0  = (const float*)d_in[7];
    const float* iv0  = (const float*)d_in[8];
    const float* w2_0 = (const float*)d_in[9];
    const float* b2_0 = (const float*)d_in[10];
    const float* W1s  = (const float*)d_in[11];
    const float* b1s  = (const float*)d_in[12];
    const float* IG   = (const float*)d_in[13];
    const float* IB   = (const float*)d_in[14];
    const float* IM   = (const float*)d_in[15];
    const float* IV   = (const float*)d_in[16];
    const float* W2s  = (const float*)d_in[17];
    const float* b2s  = (const float*)d_in[18];
    const float* OG   = (const float*)d_in[19];
    const float* OB   = (const float*)d_in[20];
    const float* OM   = (const float*)d_in[21];
    const float* OV   = (const float*)d_in[22];
    float* out = (float*)d_out;

    const int N = NN, E = NE;
    const int* src = ei;
    const int* dst = ei + E;

    char* ws = (char*)d_ws;
    size_t off = 0;
    auto alloc = [&](size_t bytes) -> void* {
        void* p = ws + off;
        off += (bytes + 255) & ~(size_t)255;
        return p;
    };
    int*   row_ptr  = (int*)alloc((N + 1) * sizeof(int));
    int*   blocksum = (int*)alloc(256 * sizeof(int));
    int*   rank     = (int*)alloc((size_t)E * sizeof(int));
    // ---- contiguous zero region ----
    char*  zbase    = ws + off;
    int*   deg      = (int*)alloc(N * sizeof(int));
    float* sums     = (float*)alloc(NG * 64 * sizeof(float));
    int*   cnt      = (int*)alloc(NG * sizeof(int));
    size_t zlen     = (ws + off) - zbase;
    // ---- rest ----
    unsigned short* col = (unsigned short*)alloc((size_t)E * sizeof(unsigned short));
    unsigned* xb    = (unsigned*)alloc((size_t)N * 64 * 4);
    unsigned short* ybuf = (unsigned short*)alloc((size_t)N * 128 * 2);
    unsigned short* hbuf = (unsigned short*)alloc((size_t)N * 64 * 2);
    unsigned short* w1t  = (unsigned short*)alloc(49152 * 2);
    unsigned short* w2t  = (unsigned short*)alloc(5 * 64 * 128 * 2);
    float* s1 = (float*)alloc(5 * 128 * sizeof(float));
    float* c1 = (float*)alloc(5 * 128 * sizeof(float));
    float* s2 = (float*)alloc(5 * 64 * sizeof(float));
    float* c2 = (float*)alloc(5 * 64 * sizeof(float));

    const int NB = (N + 255) / 256;
    const int EB = (E + 255) / 256;

    hipMemsetAsync(zbase, 0, zlen, stream);

    PrepArgs p;
    p.w1[0] = w1_0; p.w2[0] = w2_0; p.b1[0] = b1_0; p.ig[0] = ig0; p.ib[0] = ib0;
    p.im[0] = im0; p.iv[0] = iv0; p.b2[0] = b2_0;
    for (int i = 1; i < 5; ++i) {
        p.w1[i] = W1s + (size_t)(i - 1) * 64 * 128;
        p.w2[i] = W2s + (size_t)(i - 1) * 128 * 64;
        p.b1[i] = b1s + (i - 1) * 128;
        p.ig[i] = IG + (i - 1) * 128; p.ib[i] = IB + (i - 1) * 128;
        p.im[i] = IM + (i - 1) * 128; p.iv[i] = IV + (i - 1) * 128;
        p.b2[i] = b2s + (i - 1) * 64;
    }
    p.og = OG; p.ob = OB; p.om = OM; p.ov = OV;
    p.w1t[0] = w1t;
    for (int i = 1; i < 5; ++i) p.w1t[i] = w1t + 16384 + (size_t)(i - 1) * 8192;
    for (int i = 0; i < 5; ++i) {
        p.w2t[i] = w2t + (size_t)i * 8192;
        p.s1[i] = s1 + i * 128; p.c1[i] = c1 + i * 128;
        p.s2[i] = s2 + i * 64;  p.c2[i] = c2 + i * 64;
    }
    prep_kernel<<<5, 256, 0, stream>>>(p);

    // CSR: rank(hist) -> scan -> atomic-free fill
    rank_kernel<<<EB, 256, 0, stream>>>(dst, deg, rank, E);
    scan1_kernel<<<NB, 256, 0, stream>>>(deg, row_ptr, blocksum, N);
    scan2_kernel<<<1, 256, 0, stream>>>(blocksum, NB);
    scan3_kernel<<<NB, 256, 0, stream>>>(row_ptr, blocksum, N);
    fill2_kernel<<<EB, 256, 0, stream>>>(src, dst, rank, row_ptr, col, E);

    xcvt_kernel<<<(N * 64 + 255) / 256, 256, 0, stream>>>(x, xb, N * 64);

    const int MGB = (N + 63) / 64;
    const int ANB = (N + 15) / 16;   // 3125

    // layer 0
    agg_wide128<<<ANB, 256, 0, stream>>>((const uint4*)xb, row_ptr, col, (uint4*)ybuf, N);
    mlp_mfma<128><<<MGB, 256, 0, stream>>>(ybuf, hbuf, p.w1t[0], p.w2t[0],
                                           p.s1[0], p.c1[0], p.s2[0], p.c2[0], N);
    // layers 1..4
    for (int i = 1; i < 5; ++i) {
        agg_wide64<<<ANB, 256, 0, stream>>>((const uint2*)hbuf, row_ptr, col,
                                            (uint2*)ybuf, N);
        mlp_mfma<64><<<MGB, 256, 0, stream>>>(ybuf, hbuf, p.w1t[i], p.w2t[i],
                                              p.s1[i], p.c1[i], p.s2[i], p.c2[i], N);
    }

    pool_kernel<<<NB, 256, 0, stream>>>(hbuf, batch, sums, cnt, N);
    finalize_kernel<<<32, 256, 0, stream>>>(sums, cnt, out);
}